// Round 1
// baseline (1583.137 us; speedup 1.0000x reference)
//
#include <hip/hip_runtime.h>

// Problem: B=16, Q=1024, K=2048, D=1024, fp32.
// out = [context (B*Q*D) | attn (B*Q*K)] fp32, concatenated flat.

#define BM 128
#define BN 128
#define BK 32
#define LDT 132   // padded LDS stride: keeps float4 alignment, spreads banks

// Generic tiled fp32 GEMM: Out[m][n] = sum_k X[m][k] * Yop[k][n]
// TRANSB=true : Y is [N][KD] row-major (NT gemm, dot over contiguous dim)
// TRANSB=false: Y is [KD][N] row-major (NN gemm)
template <bool TRANSB>
__global__ __launch_bounds__(256, 2)
void gemm_tile(const float* __restrict__ X, const float* __restrict__ Y,
               float* __restrict__ Out,
               int ldX, int ldY, int ldO, int KD,
               long long strideX, long long strideY, long long strideO)
{
    __shared__ float As[BK][LDT];
    __shared__ float Bs[BK][LDT];

    const int b  = blockIdx.z;
    const int mt = blockIdx.y;
    const int nt = blockIdx.x;

    const float* Xb = X + (size_t)b * strideX + (size_t)mt * BM * ldX;
    const float* Yb = TRANSB ? (Y + (size_t)b * strideY + (size_t)nt * BN * ldY)
                             : (Y + (size_t)b * strideY + (size_t)nt * BN);
    float* Ob = Out + (size_t)b * strideO + (size_t)mt * BM * ldO + (size_t)nt * BN;

    const int tid = threadIdx.x;
    const int tx = tid & 15;        // output col group
    const int ty = tid >> 4;        // output row group
    const int sr = tid >> 3;        // staging row (transposed path)
    const int sc = (tid & 7) << 2;  // staging col (transposed path)
    const int br = tid >> 5;        // staging row (direct path)
    const int bc = (tid & 31) << 2; // staging col (direct path)

    float acc[8][8];
    #pragma unroll
    for (int i = 0; i < 8; ++i)
        #pragma unroll
        for (int j = 0; j < 8; ++j) acc[i][j] = 0.f;

    for (int k0 = 0; k0 < KD; k0 += BK) {
        // --- stage X tile, transposed into As[kk][row] ---
        #pragma unroll
        for (int p = 0; p < 4; ++p) {
            const float4 v = *reinterpret_cast<const float4*>(
                &Xb[(size_t)(sr + 32 * p) * ldX + k0 + sc]);
            As[sc + 0][sr + 32 * p] = v.x;
            As[sc + 1][sr + 32 * p] = v.y;
            As[sc + 2][sr + 32 * p] = v.z;
            As[sc + 3][sr + 32 * p] = v.w;
        }
        // --- stage Y tile ---
        if (TRANSB) {
            #pragma unroll
            for (int p = 0; p < 4; ++p) {
                const float4 v = *reinterpret_cast<const float4*>(
                    &Yb[(size_t)(sr + 32 * p) * ldY + k0 + sc]);
                Bs[sc + 0][sr + 32 * p] = v.x;
                Bs[sc + 1][sr + 32 * p] = v.y;
                Bs[sc + 2][sr + 32 * p] = v.z;
                Bs[sc + 3][sr + 32 * p] = v.w;
            }
        } else {
            #pragma unroll
            for (int p = 0; p < 4; ++p) {
                const float4 v = *reinterpret_cast<const float4*>(
                    &Yb[(size_t)(k0 + br + 8 * p) * ldY + bc]);
                *reinterpret_cast<float4*>(&Bs[br + 8 * p][bc]) = v;
            }
        }
        __syncthreads();

        #pragma unroll 8
        for (int kk = 0; kk < BK; ++kk) {
            const float4 a0 = *reinterpret_cast<const float4*>(&As[kk][ty * 4]);
            const float4 a1 = *reinterpret_cast<const float4*>(&As[kk][64 + ty * 4]);
            const float4 b0 = *reinterpret_cast<const float4*>(&Bs[kk][tx * 4]);
            const float4 b1 = *reinterpret_cast<const float4*>(&Bs[kk][64 + tx * 4]);
            const float av[8] = {a0.x, a0.y, a0.z, a0.w, a1.x, a1.y, a1.z, a1.w};
            const float bv[8] = {b0.x, b0.y, b0.z, b0.w, b1.x, b1.y, b1.z, b1.w};
            #pragma unroll
            for (int i = 0; i < 8; ++i)
                #pragma unroll
                for (int j = 0; j < 8; ++j)
                    acc[i][j] = fmaf(av[i], bv[j], acc[i][j]);
        }
        __syncthreads();
    }

    #pragma unroll
    for (int i = 0; i < 8; ++i) {
        const int r = (i < 4) ? (ty * 4 + i) : (64 + ty * 4 + (i - 4));
        const float4 w0 = make_float4(acc[i][0], acc[i][1], acc[i][2], acc[i][3]);
        const float4 w1 = make_float4(acc[i][4], acc[i][5], acc[i][6], acc[i][7]);
        *reinterpret_cast<float4*>(&Ob[(size_t)r * ldO + tx * 4])      = w0;
        *reinterpret_cast<float4*>(&Ob[(size_t)r * ldO + 64 + tx * 4]) = w1;
    }
}

// In-place row softmax over 2048 columns; one block per row.
__global__ __launch_bounds__(256)
void softmax_rows(float* __restrict__ P)
{
    float* p = P + (size_t)blockIdx.x * 2048;
    const int tid = threadIdx.x;

    float4 v0 = *reinterpret_cast<const float4*>(&p[tid * 4]);
    float4 v1 = *reinterpret_cast<const float4*>(&p[1024 + tid * 4]);

    float m = fmaxf(fmaxf(fmaxf(v0.x, v0.y), fmaxf(v0.z, v0.w)),
                    fmaxf(fmaxf(v1.x, v1.y), fmaxf(v1.z, v1.w)));
    #pragma unroll
    for (int off = 32; off; off >>= 1) m = fmaxf(m, __shfl_xor(m, off));

    __shared__ float red[8];
    const int wid = tid >> 6;
    if ((tid & 63) == 0) red[wid] = m;
    __syncthreads();
    m = fmaxf(fmaxf(red[0], red[1]), fmaxf(red[2], red[3]));

    v0.x = __expf(v0.x - m); v0.y = __expf(v0.y - m);
    v0.z = __expf(v0.z - m); v0.w = __expf(v0.w - m);
    v1.x = __expf(v1.x - m); v1.y = __expf(v1.y - m);
    v1.z = __expf(v1.z - m); v1.w = __expf(v1.w - m);

    float s = ((v0.x + v0.y) + (v0.z + v0.w)) + ((v1.x + v1.y) + (v1.z + v1.w));
    #pragma unroll
    for (int off = 32; off; off >>= 1) s += __shfl_xor(s, off);
    if ((tid & 63) == 0) red[4 + wid] = s;
    __syncthreads();
    const float inv = 1.0f / ((red[4] + red[5]) + (red[6] + red[7]));

    v0.x *= inv; v0.y *= inv; v0.z *= inv; v0.w *= inv;
    v1.x *= inv; v1.y *= inv; v1.z *= inv; v1.w *= inv;
    *reinterpret_cast<float4*>(&p[tid * 4]) = v0;
    *reinterpret_cast<float4*>(&p[1024 + tid * 4]) = v1;
}

extern "C" void kernel_launch(void* const* d_in, const int* in_sizes, int n_in,
                              void* d_out, int out_size, void* d_ws, size_t ws_size,
                              hipStream_t stream)
{
    const float* dec = (const float*)d_in[0];   // [16,1024,1024]
    const float* enc = (const float*)d_in[1];   // [16,2048,1024]
    float* ctx  = (float*)d_out;                         // [16,1024,1024]
    float* attn = ctx + (size_t)16 * 1024 * 1024;        // [16,1024,2048]

    // 1) scores = Dec @ Enc^T  -> written straight into the attn output region
    gemm_tile<true><<<dim3(2048 / BN, 1024 / BM, 16), 256, 0, stream>>>(
        dec, enc, attn,
        /*ldX*/1024, /*ldY*/1024, /*ldO*/2048, /*KD*/1024,
        1024LL * 1024, 2048LL * 1024, 1024LL * 2048);

    // 2) softmax rows in place
    softmax_rows<<<dim3(16 * 1024), 256, 0, stream>>>(attn);

    // 3) context = attn @ Enc
    gemm_tile<false><<<dim3(1024 / BN, 1024 / BM, 16), 256, 0, stream>>>(
        attn, enc, ctx,
        /*ldX*/2048, /*ldY*/1024, /*ldO*/1024, /*KD*/2048,
        1024LL * 2048, 2048LL * 1024, 1024LL * 1024);
}

// Round 2
// 480.865 us; speedup vs baseline: 3.2923x; 3.2923x over previous
//
#include <hip/hip_runtime.h>

// Problem: B=16, Q=1024, K=2048, D=1024, fp32.
// out = [context (B*Q*D) | attn (B*Q*K)] fp32, concatenated flat.
//
// Fast path (needs 320 MB d_ws): split-bf16 MFMA GEMM1 (hh+hl+lh, ~1e-4 score
// error), fp32 softmax (+bf16 copy), plain-bf16 MFMA GEMM2 on pre-transposed enc.
// Fallback (small ws): original fp32 VALU pipeline.

typedef __attribute__((ext_vector_type(8))) short s8v;       // 8 bf16 = 4 VGPR
typedef __attribute__((ext_vector_type(4))) float f32x4;     // MFMA acc
typedef __attribute__((ext_vector_type(8))) unsigned short us8;
typedef __attribute__((ext_vector_type(4))) unsigned short us4;

__device__ inline unsigned short f2bf(float f) {   // RNE truncate
    unsigned u = __builtin_bit_cast(unsigned, f);
    u += 0x7FFFu + ((u >> 16) & 1u);
    return (unsigned short)(u >> 16);
}
__device__ inline float bf2f(unsigned short h) {
    return __builtin_bit_cast(float, (unsigned)h << 16);
}

// ---------------- fp32 -> (bf16 hi, bf16 lo) split ----------------
__global__ __launch_bounds__(256)
void split_convert(const float* __restrict__ x, unsigned short* __restrict__ hi,
                   unsigned short* __restrict__ lo, int n4)
{
    int i = blockIdx.x * 256 + threadIdx.x;
    const int stride = gridDim.x * 256;
    for (; i < n4; i += stride) {
        const float4 v = reinterpret_cast<const float4*>(x)[i];
        us4 h, l;
        h.x = f2bf(v.x); l.x = f2bf(v.x - bf2f(h.x));
        h.y = f2bf(v.y); l.y = f2bf(v.y - bf2f(h.y));
        h.z = f2bf(v.z); l.z = f2bf(v.z - bf2f(h.z));
        h.w = f2bf(v.w); l.w = f2bf(v.w - bf2f(h.w));
        reinterpret_cast<us4*>(hi)[i] = h;
        reinterpret_cast<us4*>(lo)[i] = l;
    }
}

// ---------------- bf16 transpose: [16][2048][1024] -> [16][1024][2048] ----------------
__global__ __launch_bounds__(256)
void transpose_bf16(const unsigned short* __restrict__ in, unsigned short* __restrict__ out)
{
    __shared__ unsigned short S[64][72];   // 144B row stride: 16B-aligned, banks spread
    const int b  = blockIdx.z;
    const int kt = blockIdx.x;             // 32 tiles over K=2048
    const int dt = blockIdx.y;             // 16 tiles over D=1024
    const unsigned short* ib = in  + (size_t)b * 2048 * 1024 + (size_t)kt * 64 * 1024 + (size_t)dt * 64;
    unsigned short*       ob = out + (size_t)b * 1024 * 2048 + (size_t)dt * 64 * 2048 + (size_t)kt * 64;

    const int tid = threadIdx.x;
    const int r0 = tid >> 3, c8 = (tid & 7) * 8;
    #pragma unroll
    for (int p = 0; p < 2; ++p) {
        const int r = r0 + 32 * p;
        const us8 v = *reinterpret_cast<const us8*>(&ib[(size_t)r * 1024 + c8]);
        *reinterpret_cast<us8*>(&S[r][c8]) = v;
    }
    __syncthreads();
    const int d0 = tid >> 3, k8 = (tid & 7) * 8;
    #pragma unroll
    for (int p = 0; p < 2; ++p) {
        const int d = d0 + 32 * p;
        us8 w;
        #pragma unroll
        for (int j = 0; j < 8; ++j) w[j] = S[k8 + j][d];
        *reinterpret_cast<us8*>(&ob[(size_t)d * 2048 + k8]) = w;
    }
}

// ---------------- MFMA NT GEMM: Out[m][n] = sum_k A[m][k]*B[n][k] ----------------
// SPLIT=1: A,B given as (hi,lo) bf16 pairs; accumulate hh + hl + lh.
template<int SPLIT>
__global__ __launch_bounds__(256, 2)
void gemm_nt_mfma(const unsigned short* __restrict__ Ah, const unsigned short* __restrict__ Al,
                  const unsigned short* __restrict__ Bh, const unsigned short* __restrict__ Bl,
                  float* __restrict__ Out, int ldA, int ldB, int ldO, int K,
                  long long sA, long long sB, long long sO)
{
    constexpr int NT = SPLIT ? 4 : 2;
    __shared__ unsigned short smem[NT * 4096];     // [128][32] bf16 tiles, linear
    unsigned short* AsH = smem;
    unsigned short* BsH = smem + 4096;
    unsigned short* AsL = smem + (SPLIT ? 8192 : 0);
    unsigned short* BsL = smem + (SPLIT ? 12288 : 0);

    const int b = blockIdx.z, nt = blockIdx.x, mt = blockIdx.y;
    const int tid = threadIdx.x, lane = tid & 63, wid = tid >> 6;
    const int wm = wid >> 1, wn = wid & 1;         // 2x2 waves, 64x64 each

    const unsigned short* Ahb = Ah + b * sA + (size_t)(mt * 128) * ldA;
    const unsigned short* Bhb = Bh + b * sB + (size_t)(nt * 128) * ldB;
    const unsigned short* Alb = Al + b * sA + (size_t)(mt * 128) * ldA;
    const unsigned short* Blb = Bl + b * sB + (size_t)(nt * 128) * ldB;

    f32x4 acc[4][4];
    #pragma unroll
    for (int i = 0; i < 4; ++i)
        #pragma unroll
        for (int j = 0; j < 4; ++j) acc[i][j] = (f32x4){0.f, 0.f, 0.f, 0.f};

    const int l16 = lane * 16;
    auto stage = [&](unsigned short* tile, const unsigned short* src, int ld) {
        #pragma unroll
        for (int i = 0; i < 2; ++i) {
            const int o   = ((wid * 2 + i) << 10) + l16;   // byte offset in 8KB tile
            const int row = o >> 6;                        // 64B per row (32 bf16)
            const int ke  = (o & 63) >> 1;                 // k element offset
            __builtin_amdgcn_global_load_lds(
                (const __attribute__((address_space(1))) void*)(src + (size_t)row * ld + ke),
                (__attribute__((address_space(3))) void*)(tile + ((wid * 2 + i) << 9)),
                16, 0, 0);
        }
    };

    const int fr = lane & 15;
    const int kg = (lane >> 4) << 3;

    for (int k0 = 0; k0 < K; k0 += 32) {
        stage(AsH, Ahb + k0, ldA);
        stage(BsH, Bhb + k0, ldB);
        if (SPLIT) { stage(AsL, Alb + k0, ldA); stage(BsL, Blb + k0, ldB); }
        __syncthreads();

        s8v ah[4], bh[4], al[4], bl[4];
        #pragma unroll
        for (int f = 0; f < 4; ++f) {
            ah[f] = *reinterpret_cast<const s8v*>(&AsH[(wm * 64 + f * 16 + fr) * 32 + kg]);
            bh[f] = *reinterpret_cast<const s8v*>(&BsH[(wn * 64 + f * 16 + fr) * 32 + kg]);
            if (SPLIT) {
                al[f] = *reinterpret_cast<const s8v*>(&AsL[(wm * 64 + f * 16 + fr) * 32 + kg]);
                bl[f] = *reinterpret_cast<const s8v*>(&BsL[(wn * 64 + f * 16 + fr) * 32 + kg]);
            }
        }
        #pragma unroll
        for (int fm = 0; fm < 4; ++fm)
            #pragma unroll
            for (int fn = 0; fn < 4; ++fn) {
                acc[fm][fn] = __builtin_amdgcn_mfma_f32_16x16x32_bf16(ah[fm], bh[fn], acc[fm][fn], 0, 0, 0);
                if (SPLIT) {
                    acc[fm][fn] = __builtin_amdgcn_mfma_f32_16x16x32_bf16(ah[fm], bl[fn], acc[fm][fn], 0, 0, 0);
                    acc[fm][fn] = __builtin_amdgcn_mfma_f32_16x16x32_bf16(al[fm], bh[fn], acc[fm][fn], 0, 0, 0);
                }
            }
        __syncthreads();
    }

    // C/D: col = lane&15, row = (lane>>4)*4 + reg   [m89-verified]
    float* Ob = Out + b * sO + (size_t)(mt * 128 + wm * 64) * ldO + nt * 128 + wn * 64;
    const int cr = (lane >> 4) << 2;
    const int cc = lane & 15;
    #pragma unroll
    for (int fm = 0; fm < 4; ++fm)
        #pragma unroll
        for (int fn = 0; fn < 4; ++fn)
            #pragma unroll
            for (int r = 0; r < 4; ++r)
                Ob[(size_t)(fm * 16 + cr + r) * ldO + fn * 16 + cc] = acc[fm][fn][r];
}

// ---------------- softmax (fp32 in-place + bf16 copy) ----------------
__global__ __launch_bounds__(256)
void softmax_rows_bf(float* __restrict__ P, unsigned short* __restrict__ Pb)
{
    float* p = P + (size_t)blockIdx.x * 2048;
    unsigned short* pb = Pb + (size_t)blockIdx.x * 2048;
    const int tid = threadIdx.x;

    float4 v0 = *reinterpret_cast<const float4*>(&p[tid * 4]);
    float4 v1 = *reinterpret_cast<const float4*>(&p[1024 + tid * 4]);

    float m = fmaxf(fmaxf(fmaxf(v0.x, v0.y), fmaxf(v0.z, v0.w)),
                    fmaxf(fmaxf(v1.x, v1.y), fmaxf(v1.z, v1.w)));
    #pragma unroll
    for (int off = 32; off; off >>= 1) m = fmaxf(m, __shfl_xor(m, off));

    __shared__ float red[8];
    const int wid = tid >> 6;
    if ((tid & 63) == 0) red[wid] = m;
    __syncthreads();
    m = fmaxf(fmaxf(red[0], red[1]), fmaxf(red[2], red[3]));

    v0.x = __expf(v0.x - m); v0.y = __expf(v0.y - m);
    v0.z = __expf(v0.z - m); v0.w = __expf(v0.w - m);
    v1.x = __expf(v1.x - m); v1.y = __expf(v1.y - m);
    v1.z = __expf(v1.z - m); v1.w = __expf(v1.w - m);

    float s = ((v0.x + v0.y) + (v0.z + v0.w)) + ((v1.x + v1.y) + (v1.z + v1.w));
    #pragma unroll
    for (int off = 32; off; off >>= 1) s += __shfl_xor(s, off);
    if ((tid & 63) == 0) red[4 + wid] = s;
    __syncthreads();
    const float inv = 1.0f / ((red[4] + red[5]) + (red[6] + red[7]));

    v0.x *= inv; v0.y *= inv; v0.z *= inv; v0.w *= inv;
    v1.x *= inv; v1.y *= inv; v1.z *= inv; v1.w *= inv;
    *reinterpret_cast<float4*>(&p[tid * 4]) = v0;
    *reinterpret_cast<float4*>(&p[1024 + tid * 4]) = v1;

    us4 h0, h1;
    h0.x = f2bf(v0.x); h0.y = f2bf(v0.y); h0.z = f2bf(v0.z); h0.w = f2bf(v0.w);
    h1.x = f2bf(v1.x); h1.y = f2bf(v1.y); h1.z = f2bf(v1.z); h1.w = f2bf(v1.w);
    *reinterpret_cast<us4*>(&pb[tid * 4]) = h0;
    *reinterpret_cast<us4*>(&pb[1024 + tid * 4]) = h1;
}

// ======================= fp32 fallback path (round-1 kernels) =======================
#define BM 128
#define BN 128
#define BK 32
#define LDT 132

template <bool TRANSB>
__global__ __launch_bounds__(256, 2)
void gemm_tile(const float* __restrict__ X, const float* __restrict__ Y,
               float* __restrict__ Out,
               int ldX, int ldY, int ldO, int KD,
               long long strideX, long long strideY, long long strideO)
{
    __shared__ float As[BK][LDT];
    __shared__ float Bs[BK][LDT];
    const int b  = blockIdx.z;
    const int mt = blockIdx.y;
    const int nt = blockIdx.x;
    const float* Xb = X + (size_t)b * strideX + (size_t)mt * BM * ldX;
    const float* Yb = TRANSB ? (Y + (size_t)b * strideY + (size_t)nt * BN * ldY)
                             : (Y + (size_t)b * strideY + (size_t)nt * BN);
    float* Ob = Out + (size_t)b * strideO + (size_t)mt * BM * ldO + (size_t)nt * BN;
    const int tid = threadIdx.x;
    const int tx = tid & 15;
    const int ty = tid >> 4;
    const int sr = tid >> 3;
    const int sc = (tid & 7) << 2;
    const int br = tid >> 5;
    const int bc = (tid & 31) << 2;
    float acc[8][8];
    #pragma unroll
    for (int i = 0; i < 8; ++i)
        #pragma unroll
        for (int j = 0; j < 8; ++j) acc[i][j] = 0.f;
    for (int k0 = 0; k0 < KD; k0 += BK) {
        #pragma unroll
        for (int p = 0; p < 4; ++p) {
            const float4 v = *reinterpret_cast<const float4*>(
                &Xb[(size_t)(sr + 32 * p) * ldX + k0 + sc]);
            As[sc + 0][sr + 32 * p] = v.x;
            As[sc + 1][sr + 32 * p] = v.y;
            As[sc + 2][sr + 32 * p] = v.z;
            As[sc + 3][sr + 32 * p] = v.w;
        }
        if (TRANSB) {
            #pragma unroll
            for (int p = 0; p < 4; ++p) {
                const float4 v = *reinterpret_cast<const float4*>(
                    &Yb[(size_t)(sr + 32 * p) * ldY + k0 + sc]);
                Bs[sc + 0][sr + 32 * p] = v.x;
                Bs[sc + 1][sr + 32 * p] = v.y;
                Bs[sc + 2][sr + 32 * p] = v.z;
                Bs[sc + 3][sr + 32 * p] = v.w;
            }
        } else {
            #pragma unroll
            for (int p = 0; p < 4; ++p) {
                const float4 v = *reinterpret_cast<const float4*>(
                    &Yb[(size_t)(k0 + br + 8 * p) * ldY + bc]);
                *reinterpret_cast<float4*>(&Bs[br + 8 * p][bc]) = v;
            }
        }
        __syncthreads();
        #pragma unroll 8
        for (int kk = 0; kk < BK; ++kk) {
            const float4 a0 = *reinterpret_cast<const float4*>(&As[kk][ty * 4]);
            const float4 a1 = *reinterpret_cast<const float4*>(&As[kk][64 + ty * 4]);
            const float4 b0 = *reinterpret_cast<const float4*>(&Bs[kk][tx * 4]);
            const float4 b1 = *reinterpret_cast<const float4*>(&Bs[kk][64 + tx * 4]);
            const float av[8] = {a0.x, a0.y, a0.z, a0.w, a1.x, a1.y, a1.z, a1.w};
            const float bv[8] = {b0.x, b0.y, b0.z, b0.w, b1.x, b1.y, b1.z, b1.w};
            #pragma unroll
            for (int i = 0; i < 8; ++i)
                #pragma unroll
                for (int j = 0; j < 8; ++j)
                    acc[i][j] = fmaf(av[i], bv[j], acc[i][j]);
        }
        __syncthreads();
    }
    #pragma unroll
    for (int i = 0; i < 8; ++i) {
        const int r = (i < 4) ? (ty * 4 + i) : (64 + ty * 4 + (i - 4));
        const float4 w0 = make_float4(acc[i][0], acc[i][1], acc[i][2], acc[i][3]);
        const float4 w1 = make_float4(acc[i][4], acc[i][5], acc[i][6], acc[i][7]);
        *reinterpret_cast<float4*>(&Ob[(size_t)r * ldO + tx * 4])      = w0;
        *reinterpret_cast<float4*>(&Ob[(size_t)r * ldO + 64 + tx * 4]) = w1;
    }
}

__global__ __launch_bounds__(256)
void softmax_rows(float* __restrict__ P)
{
    float* p = P + (size_t)blockIdx.x * 2048;
    const int tid = threadIdx.x;
    float4 v0 = *reinterpret_cast<const float4*>(&p[tid * 4]);
    float4 v1 = *reinterpret_cast<const float4*>(&p[1024 + tid * 4]);
    float m = fmaxf(fmaxf(fmaxf(v0.x, v0.y), fmaxf(v0.z, v0.w)),
                    fmaxf(fmaxf(v1.x, v1.y), fmaxf(v1.z, v1.w)));
    #pragma unroll
    for (int off = 32; off; off >>= 1) m = fmaxf(m, __shfl_xor(m, off));
    __shared__ float red[8];
    const int wid = tid >> 6;
    if ((tid & 63) == 0) red[wid] = m;
    __syncthreads();
    m = fmaxf(fmaxf(red[0], red[1]), fmaxf(red[2], red[3]));
    v0.x = __expf(v0.x - m); v0.y = __expf(v0.y - m);
    v0.z = __expf(v0.z - m); v0.w = __expf(v0.w - m);
    v1.x = __expf(v1.x - m); v1.y = __expf(v1.y - m);
    v1.z = __expf(v1.z - m); v1.w = __expf(v1.w - m);
    float s = ((v0.x + v0.y) + (v0.z + v0.w)) + ((v1.x + v1.y) + (v1.z + v1.w));
    #pragma unroll
    for (int off = 32; off; off >>= 1) s += __shfl_xor(s, off);
    if ((tid & 63) == 0) red[4 + wid] = s;
    __syncthreads();
    const float inv = 1.0f / ((red[4] + red[5]) + (red[6] + red[7]));
    v0.x *= inv; v0.y *= inv; v0.z *= inv; v0.w *= inv;
    v1.x *= inv; v1.y *= inv; v1.z *= inv; v1.w *= inv;
    *reinterpret_cast<float4*>(&p[tid * 4]) = v0;
    *reinterpret_cast<float4*>(&p[1024 + tid * 4]) = v1;
}

// =========================== launcher ===========================
extern "C" void kernel_launch(void* const* d_in, const int* in_sizes, int n_in,
                              void* d_out, int out_size, void* d_ws, size_t ws_size,
                              hipStream_t stream)
{
    const float* dec = (const float*)d_in[0];   // [16,1024,1024]
    const float* enc = (const float*)d_in[1];   // [16,2048,1024]
    float* ctx  = (float*)d_out;                        // [16,1024,1024]
    float* attn = ctx + (size_t)16 * 1024 * 1024;       // [16,1024,2048]

    const long long DECN = 16LL * 1024 * 1024;          // 16.78M
    const long long ENCN = 16LL * 2048 * 1024;          // 33.55M
    const size_t NEED = (size_t)(2 * DECN + 4 * ENCN) * 2;  // 320 MB

    if (ws_size >= NEED) {
        unsigned short* decH  = (unsigned short*)d_ws;
        unsigned short* decL  = decH + DECN;
        unsigned short* encH  = decL + DECN;
        unsigned short* encL  = encH + ENCN;
        unsigned short* encT  = encL + ENCN;   // [16][1024][2048]
        unsigned short* attnB = encT + ENCN;   // [16][1024][2048]

        split_convert<<<2048, 256, 0, stream>>>(dec, decH, decL, (int)(DECN / 4));
        split_convert<<<2048, 256, 0, stream>>>(enc, encH, encL, (int)(ENCN / 4));
        transpose_bf16<<<dim3(32, 16, 16), 256, 0, stream>>>(encH, encT);

        // scores = dec @ enc^T  (split bf16, into attn region)
        gemm_nt_mfma<1><<<dim3(16, 8, 16), 256, 0, stream>>>(
            decH, decL, encH, encL, attn,
            1024, 1024, 2048, 1024,
            1024LL * 1024, 2048LL * 1024, 1024LL * 2048);

        softmax_rows_bf<<<16 * 1024, 256, 0, stream>>>(attn, attnB);

        // context = attn @ enc  ==  attnB (NT) encT
        gemm_nt_mfma<0><<<dim3(8, 8, 16), 256, 0, stream>>>(
            attnB, attnB, encT, encT, ctx,
            2048, 2048, 1024, 2048,
            1024LL * 2048, 1024LL * 2048, 1024LL * 1024);
    } else {
        gemm_tile<true><<<dim3(2048 / BN, 1024 / BM, 16), 256, 0, stream>>>(
            dec, enc, attn, 1024, 1024, 2048, 1024,
            1024LL * 1024, 2048LL * 1024, 1024LL * 2048);
        softmax_rows<<<dim3(16 * 1024), 256, 0, stream>>>(attn);
        gemm_tile<false><<<dim3(1024 / BN, 1024 / BM, 16), 256, 0, stream>>>(
            attn, enc, ctx, 2048, 1024, 1024, 2048,
            1024LL * 2048, 2048LL * 1024, 1024LL * 1024);
    }
}